// Round 9
// baseline (8629.512 us; speedup 1.0000x reference)
//
#include <hip/hip_runtime.h>
#include <stdint.h>
#include <math.h>

// Decoder: autoregressive GRU (B=128,H=512,T=256) -> LSTM (L=1024) -> FC (V=1024)
// fp32 I/O. Internal math fp32; GEMMs via MFMA 16x16x32 bf16 with split-bf16
// (hi/lo) weights AND activations, 3-pass MFMA.
//
// Round 13: OCCUPANCY / LATENCY-HIDING. Eliminated by measurement: sync
// (2.1us/gen probe), LLC bytes (ring null), L2 channels (tiling null), L2
// fills (FETCH 6.6x with zero time delta), LDS weight conflicts, HBM. What
// fits everything: per-CU load throughput ~30 GB/s in BOTH kernels = the
// outstanding-miss ceiling of 8 waves/CU (25% occupancy). Fix: LSTM blocks
// widen to 1024 threads (16 waves/CU), split-K inside the block -- wave-set A
// does seq[0:256)+h[0:512), set B does seq[256:512)+h[512:1024), partials
// summed via glds[2]; FC k-split 8 ways. Per-block bytes UNCHANGED; in-flight
// loads 2x. Grid stays 256 blocks (barrier topology untouched). GRU unchanged
// (control). h/x tiled layouts and seq rotation kept from round 12.

typedef unsigned short u16;
typedef unsigned int u32;
typedef __attribute__((ext_vector_type(8))) short short8;   // 8 bf16 = 4 VGPR
typedef __attribute__((ext_vector_type(4))) float float4_;  // MFMA acc

#define MFMA(a, b, c) __builtin_amdgcn_mfma_f32_16x16x32_bf16((a), (b), (c), 0, 0, 0)

// System-coherent (LLC) 16B load, bypasses L1+L2; usable only after an owning wait.
#define SC_LOAD(dst, ptr) \
  asm volatile("global_load_dwordx4 %0, %1, off sc0 sc1" : "=v"(dst) : "v"(ptr) : "memory")
// s_waitcnt that also "owns" 8 loaded regs so consumers can't be hoisted above it.
#define WAIT8(n, a0,a1,a2,a3,a4,a5,a6,a7) \
  asm volatile("s_waitcnt vmcnt(" #n ")" \
    : "+v"(a0),"+v"(a1),"+v"(a2),"+v"(a3),"+v"(a4),"+v"(a5),"+v"(a6),"+v"(a7) :: "memory")
// Coherent 2B store (write-through to LLC, complete when vmcnt retires).
#define SC_STORE16(ptr, val) \
  asm volatile("global_store_short %0, %1, off sc0 sc1" :: "v"(ptr), "v"((u32)(val)) : "memory")

__device__ __forceinline__ float bf2f(u16 u) {
  union { u32 i; float f; } v; v.i = ((u32)u) << 16; return v.f;
}
__device__ __forceinline__ u16 f2bf(float f) {
  union { float f; u32 i; } v; v.f = f;
  u32 x = v.i;
  return (u16)((x + 0x7fffu + ((x >> 16) & 1u)) >> 16);  // RNE, finite inputs only
}
__device__ __forceinline__ void split2(float w, u16& h, u16& l) {
  h = f2bf(w); l = f2bf(w - bf2f(h));
}
__device__ __forceinline__ float sigm(float x) { return 1.0f / (1.0f + expf(-x)); }

__device__ __forceinline__ void frag_from_f32(const float* p, short8& hi, short8& lo) {
  short8 h, l;
#pragma unroll
  for (int j = 0; j < 8; ++j) {
    u16 a, b; split2(p[j], a, b);
    h[j] = (short)a; l[j] = (short)b;
  }
  hi = h; lo = l;
}

// System-scope acquire: s_waitcnt + buffer_inv (invalidate-only, preserves dirty).
__device__ __forceinline__ void cache_acquire() {
  __builtin_amdgcn_fence(__ATOMIC_ACQUIRE, "");
}

// --- Flat group barrier (no root) ------------------------------------------
__device__ __forceinline__ void bar_arrive(u32* grp) {
  asm volatile("s_waitcnt vmcnt(0)" ::: "memory");
  __syncthreads();
  if (threadIdx.x == 0) atomicAdd(grp, 1u);
}
template<int NG>
__device__ __forceinline__ void bar_wait_poll(u32* grpb, u32 target) {
  if (threadIdx.x < 64) {
    u32* p = grpb + (size_t)(threadIdx.x & (NG - 1)) * 32;
    while (true) {
      u32 v = __hip_atomic_load(p, __ATOMIC_RELAXED, __HIP_MEMORY_SCOPE_AGENT);
      if (__all((int)(v >= target))) break;
      __builtin_amdgcn_s_sleep(1);
    }
  }
  __syncthreads();
}

// Tile-layout offset helpers (u16 units).
// x slot plane: 128 rows x 512 cols -> tiles (r>>4, k>>5), tile = 16x32 = 512 u16.
__device__ __forceinline__ size_t xoff(int r, int k) {
  return ((size_t)((r >> 4) * 16 + (k >> 5))) * 512 + (r & 15) * 32 + (k & 31);
}
// h slot plane: 128 rows x 1024 cols -> tiles (r>>4, k>>5), tile = 16x32 = 512 u16.
__device__ __forceinline__ size_t hoff(int r, int k) {
  return ((size_t)((r >> 4) * 32 + (k >> 5))) * 512 + (r & 15) * 32 + (k & 31);
}

// ---------------------------------------------------------------------------
// Kernel 1: persistent GRU chain. 128 blocks x 256 threads. 16 groups of 8.
// UNCHANGED from round 12 (control).
// ---------------------------------------------------------------------------
template<int C>
__global__ __launch_bounds__(256)
void gru_chain(const float* __restrict__ z,
               const float* __restrict__ Wih, const float* __restrict__ Whh,
               const float* __restrict__ bih, const float* __restrict__ bhh,
               u16* outu, u16* __restrict__ xpp, u32* grpb) {
  __shared__ __align__(16) u16 wh_lds[48 * 520];
  __shared__ __align__(16) u16 wl_lds[48 * 520];
  __shared__ float blds[32];

  const int tid = threadIdx.x;
  const int wg = blockIdx.x;
  const int grp = wg & 63;
  const int mhalf = wg >> 6;
  const int jb = grp * 8;
  u32* const mygrp = grpb + (size_t)(wg >> 3) * 32;   // 16 groups of 8, 128B apart

  for (int idx = tid; idx < 48 * 512; idx += 256) {
    int row = idx >> 9, k = idx & 511;
    int t3 = row >> 4, n = row & 15;
    int grow = t3 * 512 + jb + (n & 7);
    float w = ((n < 8) ? Wih : Whh)[(size_t)grow * 512 + k];
    u16 h, l; split2(w, h, l);
    wh_lds[row * 520 + k] = h;
    wl_lds[row * 520 + k] = l;
  }
  if (tid < 8) {
    blds[tid]      = bih[jb + tid] + bhh[jb + tid];
    blds[8 + tid]  = bih[512 + jb + tid] + bhh[512 + jb + tid];
    blds[16 + tid] = bih[1024 + jb + tid];
    blds[24 + tid] = bhh[1024 + jb + tid];
  }
  __syncthreads();

  const int lane = tid & 63, wv = tid >> 6;
  const int n16 = lane & 15, q = lane >> 4;
  const int j8 = n16 & 7;
  const int mrow = mhalf * 64 + wv * 16 + n16;
  const int orow0 = mhalf * 64 + wv * 16 + q * 4;
  const bool act = (n16 < 8);
  const int col = jb + j8;
  const int qo = q * 8;
  const int xg = mhalf * 4 + wv;          // mrow >> 4 (tile row-group)

  float x_own[4];

  // ---- step 1: x1 = GRU(x=0, h=z); A = z hi/lo (normal cached loads) ----
  {
    float4_ acc0 = {0.f, 0.f, 0.f, 0.f}, acc1 = acc0, acc2 = acc0;
    for (int ki = 0; ki < 16; ++ki) {
      const int ko = ki * 32 + qo;
      short8 ah, al;
      frag_from_f32(z + (size_t)mrow * 512 + ko, ah, al);
      short8 b0h = *(const short8*)(wh_lds + (0 * 16 + n16) * 520 + ko);
      short8 b1h = *(const short8*)(wh_lds + (1 * 16 + n16) * 520 + ko);
      short8 b2h = *(const short8*)(wh_lds + (2 * 16 + n16) * 520 + ko);
      short8 b0l = *(const short8*)(wl_lds + (0 * 16 + n16) * 520 + ko);
      short8 b1l = *(const short8*)(wl_lds + (1 * 16 + n16) * 520 + ko);
      short8 b2l = *(const short8*)(wl_lds + (2 * 16 + n16) * 520 + ko);
      acc0 = MFMA(ah, b0h, acc0); acc0 = MFMA(al, b0h, acc0); acc0 = MFMA(ah, b0l, acc0);
      acc1 = MFMA(ah, b1h, acc1); acc1 = MFMA(al, b1h, acc1); acc1 = MFMA(ah, b1l, acc1);
      acc2 = MFMA(ah, b2h, acc2); acc2 = MFMA(al, b2h, acc2); acc2 = MFMA(ah, b2l, acc2);
    }
    for (int reg = 0; reg < 4; ++reg) {
      float pr = __shfl_xor(acc0[reg], 8);
      float pz = __shfl_xor(acc1[reg], 8);
      float pn = __shfl_xor(acc2[reg], 8);
      float r  = sigm(pr + blds[j8]);
      float zg = sigm(pz + blds[8 + j8]);
      float nn = tanhf(blds[16 + j8] + r * (pn + blds[24 + j8]));
      float hv = act ? z[(size_t)(orow0 + reg) * 512 + col] : 0.f;
      float xn = (1.f - zg) * nn + zg * hv;
      x_own[reg] = xn;
      if (act) {
        size_t po = xoff(orow0 + reg, col);
        u16 h, l; split2(xn, h, l);
        SC_STORE16(xpp + (size_t)1 * 131072 + po, h);           // slot 1 hi
        SC_STORE16(xpp + (size_t)1 * 131072 + 65536 + po, l);   // slot 1 lo
      }
    }
  }
  bar_arrive(mygrp);                          // gen 1
  if (act) {                                  // seq stores overlap the wait
    for (int reg = 0; reg < 4; ++reg) {
      int row = orow0 + reg;
      float rl = fmaxf(x_own[reg], 0.f);
      u16 rh, rlo; split2(rl, rh, rlo);
      size_t B = ((size_t)row * 256 + 1) * 2048;
      u32 rot = (u32)(row & 15) * 128;
      outu[B + ((rot + col) & 2047)] = rh;
      outu[B + ((rot + 512 + col) & 2047)] = rlo;
    }
  }
  bar_wait_poll<16>(grpb, 8u);

  // ---- steps 2..255: A = x_{t-1} hi/lo ----
  for (int t = 2; t < 256; ++t) {
    if constexpr (C > 0) {
      if ((t & (C - 1)) == 0) cache_acquire();   // kill stale ring lines
    }
    const size_t sr = (C > 0) ? (size_t)((t - 1) & (C - 1)) : (size_t)((t - 1) & 1);
    const size_t sw = (C > 0) ? (size_t)(t & (C - 1))       : (size_t)(t & 1);
    // tiled consumer base: tile (xg, ki), lane offset n16*32 + qo (contiguous 1KB/wave)
    const u16* xh = xpp + sr * 131072 + (size_t)xg * 16 * 512 + n16 * 32 + qo;
    const u16* xl = xh + 65536;
    short8 bufh[16], bufl[16];
    if constexpr (C > 0) {
#pragma unroll
      for (int ki = 0; ki < 16; ++ki) {
        bufh[ki] = *(const short8*)(xh + ki * 512);
        bufl[ki] = *(const short8*)(xl + ki * 512);
      }
    } else {
#pragma unroll
      for (int ki = 0; ki < 16; ++ki) {
        SC_LOAD(bufh[ki], xh + ki * 512);
        SC_LOAD(bufl[ki], xl + ki * 512);
      }
      WAIT8(0, bufh[0], bufh[1], bufh[2], bufh[3], bufh[4], bufh[5], bufh[6], bufh[7]);
      WAIT8(0, bufh[8], bufh[9], bufh[10], bufh[11], bufh[12], bufh[13], bufh[14], bufh[15]);
      WAIT8(0, bufl[0], bufl[1], bufl[2], bufl[3], bufl[4], bufl[5], bufl[6], bufl[7]);
      WAIT8(0, bufl[8], bufl[9], bufl[10], bufl[11], bufl[12], bufl[13], bufl[14], bufl[15]);
    }

    float4_ acc0 = {0.f, 0.f, 0.f, 0.f}, acc1 = acc0, acc2 = acc0;
#pragma unroll
    for (int ki = 0; ki < 16; ++ki) {
      const int ko = ki * 32 + qo;
      short8 b0h = *(const short8*)(wh_lds + (0 * 16 + n16) * 520 + ko);
      short8 b1h = *(const short8*)(wh_lds + (1 * 16 + n16) * 520 + ko);
      short8 b2h = *(const short8*)(wh_lds + (2 * 16 + n16) * 520 + ko);
      short8 b0l = *(const short8*)(wl_lds + (0 * 16 + n16) * 520 + ko);
      short8 b1l = *(const short8*)(wl_lds + (1 * 16 + n16) * 520 + ko);
      short8 b2l = *(const short8*)(wl_lds + (2 * 16 + n16) * 520 + ko);
      acc0 = MFMA(bufh[ki], b0h, acc0); acc0 = MFMA(bufl[ki], b0h, acc0); acc0 = MFMA(bufh[ki], b0l, acc0);
      acc1 = MFMA(bufh[ki], b1h, acc1); acc1 = MFMA(bufl[ki], b1h, acc1); acc1 = MFMA(bufh[ki], b1l, acc1);
      acc2 = MFMA(bufh[ki], b2h, acc2); acc2 = MFMA(bufl[ki], b2h, acc2); acc2 = MFMA(bufh[ki], b2l, acc2);
    }
    // compute x_t and store the ring FIRST (the only data other blocks need)
    for (int reg = 0; reg < 4; ++reg) {
      float ar = acc0[reg], az = acc1[reg], an = acc2[reg];
      float pr = __shfl_xor(ar, 8), pz = __shfl_xor(az, 8), pn = __shfl_xor(an, 8);
      float r  = sigm(ar + pr + blds[j8]);
      float zg = sigm(az + pz + blds[8 + j8]);
      float nn = tanhf(an + blds[16 + j8] + r * (pn + blds[24 + j8]));
      float xn = (1.f - zg) * nn + zg * x_own[reg];
      x_own[reg] = xn;
      if (act) {
        size_t po = xoff(orow0 + reg, col);
        u16 h, l; split2(xn, h, l);
        SC_STORE16(xpp + sw * 131072 + po, h);
        SC_STORE16(xpp + sw * 131072 + 65536 + po, l);
      }
    }
    if (t < 255) bar_arrive(mygrp);           // gen t
    if (act) {                                // seq stores overlap the wait
      for (int reg = 0; reg < 4; ++reg) {
        int row = orow0 + reg;
        float rl = fmaxf(x_own[reg], 0.f);
        u16 rh, rlo; split2(rl, rh, rlo);
        size_t B = ((size_t)row * 256 + (size_t)t) * 2048;
        u32 rot = (u32)(row & 15) * 128;
        outu[B + ((rot + col) & 2047)] = rh;
        outu[B + ((rot + 512 + col) & 2047)] = rlo;
      }
    }
    if (t < 255) bar_wait_poll<16>(grpb, (u32)t * 8u);
  }
}

// ---------------------------------------------------------------------------
// Kernel 2: persistent LSTM chain with fused FC. 256 blocks x 1024 THREADS
// (16 waves/CU, 50% occupancy). Wave-set ks=wv16>>3 splits K: each set does
// seq half (pre-wait) + 2 h-chunks (post-wait); partials summed via glds[2].
// FC k-split 8 ways (fkq = wv16>>1, 128 k each). Ring mode only (C >= 8).
// 32 groups of 8 blocks; early arrive after h-store drain.
// ---------------------------------------------------------------------------
template<int C>
__global__ __launch_bounds__(1024)
void lstm_fc_chain(const float* __restrict__ Wih, const float* __restrict__ Whh,
                   const float* __restrict__ bih, const float* __restrict__ bhh,
                   const float* __restrict__ fcW, const float* __restrict__ fcb,
                   u16* __restrict__ hpp, u16* outu, float* outf, u32* grpb) {
  static_assert(C >= 8, "LSTM requires ring mode");
  __shared__ __align__(16) u16 whh_hi[16 * 1024];
  __shared__ __align__(16) u16 whh_lo[16 * 1024];
  __shared__ __align__(16) u16 wih_hi[16 * 512];
  __shared__ __align__(16) u16 wih_lo[16 * 512];
  __shared__ float glds[2][128][17];
  __shared__ float pglds[2][16][8][16];
  __shared__ float bclds[16];
  __shared__ float fclds[16];

  const int tid = threadIdx.x;
  const int s = blockIdx.x;
  const int colbase = s * 4;
  const int vt = s & 63, bq = s >> 6;
  const int vbase = vt * 16;
  u32* const mygrp = grpb + (size_t)(s >> 3) * 32;   // 32 groups of 8, 128B apart

  for (int idx = tid; idx < 16 * 1024; idx += 1024) {
    int row = idx >> 10, k = idx & 1023;
    int gate = row >> 2, cc = row & 3;
    float w = Whh[(size_t)(gate * 1024 + colbase + cc) * 1024 + k];
    u16 h, l; split2(w, h, l);
    int ks2 = k ^ ((row & 7) << 3);           // bank swizzle (bijective per row)
    whh_hi[row * 1024 + ks2] = h;
    whh_lo[row * 1024 + ks2] = l;
  }
  for (int idx = tid; idx < 16 * 512; idx += 1024) {
    int row = idx >> 9, k = idx & 511;
    int gate = row >> 2, cc = row & 3;
    float w = Wih[(size_t)(gate * 1024 + colbase + cc) * 512 + k];
    u16 h, l; split2(w, h, l);
    int ks2 = k ^ ((row & 7) << 3);
    wih_hi[row * 512 + ks2] = h;
    wih_lo[row * 512 + ks2] = l;
  }
  if (tid < 16) {
    int gate = tid >> 2, cc = tid & 3;
    int wcol = gate * 1024 + colbase + cc;
    bclds[tid] = bih[wcol] + bhh[wcol];
    fclds[tid] = fcb[vbase + tid];
  }
  __syncthreads();

  const int lane = tid & 63, wv16 = tid >> 6;   // 16 waves
  const int wv = wv16 & 7;                      // row-group 0..7
  const int ks = wv16 >> 3;                     // K-set 0/1
  const int n16 = lane & 15, q = lane >> 4;
  const int qo = q * 8;
  const int nsw = (n16 & 7) << 3;               // per-lane weight read swizzle
  const int arow = wv * 16 + n16;
  const int myrow = tid >> 2, mycol = tid & 3;  // valid for tid < 512
  const int fmt = wv16 & 1, fkq = wv16 >> 1;    // FC: 2 x 8 split
  const int fkbase = fkq * 128;
  const int fg = bq * 2 + fmt;                  // frow >> 4 (tile row-group)

  short8 brh[4], brl[4];
  for (int i = 0; i < 4; ++i)
    frag_from_f32(fcW + (size_t)(vbase + n16) * 1024 + fkbase + i * 32 + qo,
                  brh[i], brl[i]);

  float c = 0.f;

  // t = 0: preacts are just biases; write h_0 into slot 0, arrive gen 1.
  if (tid < 512) {
    float pi = bclds[mycol], pg = bclds[8 + mycol], po = bclds[12 + mycol];
    c = sigm(pi) * tanhf(pg);
    float h = sigm(po) * tanhf(c);
    size_t off = hoff(myrow, colbase + mycol);
    u16 hh, hl; split2(h, hh, hl);
    SC_STORE16(hpp + off, hh);
    SC_STORE16(hpp + 131072 + off, hl);
  }
  bar_arrive(mygrp);   // gen 1

  for (int t = 1; t < 256; ++t) {
    const size_t sr = (size_t)((t - 1) & (C - 1));
    const size_t sw = (size_t)(t & (C - 1));

    // ---- pre-wait: this set's seq half (depends only on seq, hides the wait)
    float4_ acc = {0.f, 0.f, 0.f, 0.f};
    {
      const u16* sqB = outu + ((size_t)arow * 256 + t) * 2048;
      const int rot = n16 * 128;              // (arow & 15) * 128
#pragma unroll
      for (int kk = 0; kk < 8; ++kk) {
        const int ki = ks * 8 + kk;
        const int ko = ki * 32 + qo;
        const int kw = ko ^ nsw;
        short8 sh = *(const short8*)(sqB + ((rot + ko) & 2047));
        short8 sl = *(const short8*)(sqB + ((rot + 512 + ko) & 2047));
        short8 bh = *(const short8*)(wih_hi + n16 * 512 + kw);
        short8 bl = *(const short8*)(wih_lo + n16 * 512 + kw);
        acc = MFMA(sh, bh, acc); acc = MFMA(sl, bh, acc); acc = MFMA(sh, bl, acc);
      }
    }

    if ((t & (C - 1)) == 0) cache_acquire();   // kill stale ring lines
    bar_wait_poll<32>(grpb, (u32)t * 8u);      // h_{t-1} now visible

    // ---- post-wait: this set's 2 h-chunks (tiled reads, 1KB/wave/load-row)
    const u16* ph = hpp + sr * 262144 + (size_t)wv * 32 * 512 + n16 * 32 + qo;
    const u16* pl = ph + 131072;
#pragma unroll
    for (int cc2 = 0; cc2 < 2; ++cc2) {
      const int ch = ks * 2 + cc2;
      short8 hb[8], lb[8];
#pragma unroll
      for (int j = 0; j < 8; ++j) {
        hb[j] = *(const short8*)(ph + (ch * 8 + j) * 512);
        lb[j] = *(const short8*)(pl + (ch * 8 + j) * 512);
      }
#pragma unroll
      for (int j = 0; j < 8; ++j) {
        const int ko = (ch * 8 + j) * 32 + qo;
        const int kw = ko ^ nsw;
        short8 bh = *(const short8*)(whh_hi + n16 * 1024 + kw);
        short8 bl = *(const short8*)(whh_lo + n16 * 1024 + kw);
        acc = MFMA(hb[j], bh, acc);
        acc = MFMA(lb[j], bh, acc);
        acc = MFMA(hb[j], bl, acc);
      }
    }
    for (int reg = 0; reg < 4; ++reg)
      glds[ks][wv * 16 + q * 4 + reg][n16] = acc[reg];
    __syncthreads();
    if (tid < 512) {
      float pi = glds[0][myrow][mycol]      + glds[1][myrow][mycol]      + bclds[mycol];
      float pf = glds[0][myrow][4 + mycol]  + glds[1][myrow][4 + mycol]  + bclds[4 + mycol];
      float pg = glds[0][myrow][8 + mycol]  + glds[1][myrow][8 + mycol]  + bclds[8 + mycol];
      float po = glds[0][myrow][12 + mycol] + glds[1][myrow][12 + mycol] + bclds[12 + mycol];
      c = sigm(pf) * c + sigm(pi) * tanhf(pg);
      float h = sigm(po) * tanhf(c);
      size_t off = hoff(myrow, colbase + mycol);
      u16 hh, hl; split2(h, hh, hl);
      SC_STORE16(hpp + sw * 262144 + off, hh);
      SC_STORE16(hpp + sw * 262144 + 131072 + off, hl);
    }

    // early arrive: the FC below is not consumed by other blocks; slot sr is
    // not rewritten for >= C-1 >= 7 generations.
    bar_arrive(mygrp);   // gen t+1

    // fused FC: logits_{t-1} from h_{t-1} (slot sr), tiled reads, k-split 8
    {
      const u16* fh = hpp + sr * 262144 + ((size_t)fg * 32 + fkq * 4) * 512 + n16 * 32 + qo;
      const u16* fl = fh + 131072;
      short8 fhb[4], flb[4];
#pragma unroll
      for (int i = 0; i < 4; ++i) {
        fhb[i] = *(const short8*)(fh + i * 512);
        flb[i] = *(const short8*)(fl + i * 512);
      }
      float4_ lacc = {0.f, 0.f, 0.f, 0.f};
#pragma unroll
      for (int i = 0; i < 4; ++i) {
        lacc = MFMA(fhb[i], brh[i], lacc);
        lacc = MFMA(flb[i], brh[i], lacc);
        lacc = MFMA(fhb[i], brl[i], lacc);
      }
      for (int reg = 0; reg < 4; ++reg)
        pglds[fmt][q * 4 + reg][fkq][n16] = lacc[reg];
      __syncthreads();
      if (tid < 512) {
        int trow = tid >> 4, tcol = tid & 15;
        const float* pg8 = &pglds[trow >> 4][trow & 15][0][tcol];
        float lsum = fclds[tcol];
#pragma unroll
        for (int f = 0; f < 8; ++f) lsum += pg8[f * 16];
        outf[((size_t)(bq * 32 + trow) * 256 + (t - 1)) * 1024 + vbase + tcol] = lsum;
      }
    }
  }

  // epilogue: logits_255 from h_255 (slot 255&(C-1); fence first -- that
  // slot's addresses were last read C steps ago)
  {
    bar_wait_poll<32>(grpb, 256u * 8u);
    cache_acquire();
    const size_t sl = (size_t)(255 & (C - 1));
    const u16* fh = hpp + sl * 262144 + ((size_t)fg * 32 + fkq * 4) * 512 + n16 * 32 + qo;
    const u16* fl = fh + 131072;
    short8 fhb[4], flb[4];
#pragma unroll
    for (int i = 0; i < 4; ++i) {
      fhb[i] = *(const short8*)(fh + i * 512);
      flb[i] = *(const short8*)(fl + i * 512);
    }
    float4_ lacc = {0.f, 0.f, 0.f, 0.f};
#pragma unroll
    for (int i = 0; i < 4; ++i) {
      lacc = MFMA(fhb[i], brh[i], lacc);
      lacc = MFMA(flb[i], brh[i], lacc);
      lacc = MFMA(fhb[i], brl[i], lacc);
    }
    for (int reg = 0; reg < 4; ++reg)
      pglds[fmt][q * 4 + reg][fkq][n16] = lacc[reg];
    __syncthreads();
    if (tid < 512) {
      int trow = tid >> 4, tcol = tid & 15;
      const float* pg8 = &pglds[trow >> 4][trow & 15][0][tcol];
      float lsum = fclds[tcol];
#pragma unroll
      for (int f = 0; f < 8; ++f) lsum += pg8[f * 16];
      outf[((size_t)(bq * 32 + trow) * 256 + 255) * 1024 + vbase + tcol] = lsum;
    }
  }
}

// ---------------------------------------------------------------------------
extern "C" void kernel_launch(void* const* d_in, const int* in_sizes, int n_in,
                              void* d_out, int out_size, void* d_ws, size_t ws_size,
                              hipStream_t stream) {
  (void)in_sizes; (void)n_in; (void)out_size;
  const float* z    = (const float*)d_in[0];
  const float* gWih = (const float*)d_in[2];
  const float* gWhh = (const float*)d_in[3];
  const float* gbih = (const float*)d_in[4];
  const float* gbhh = (const float*)d_in[5];
  const float* lWih = (const float*)d_in[6];
  const float* lWhh = (const float*)d_in[7];
  const float* lbih = (const float*)d_in[8];
  const float* lbhh = (const float*)d_in[9];
  const float* fcW  = (const float*)d_in[10];
  const float* fcb  = (const float*)d_in[11];

  const size_t XS = 262144;   // x slot bytes (2 planes x 128x512 bf16, tiled)
  const size_t HS = 524288;   // h slot bytes (2 planes x 128x1024 bf16, tiled)
  const size_t BAR = 8192;    // barrier region: 32 LSTM + 16 GRU group lines

  char* w = (char*)d_ws;
  u32* grpL = (u32*)(w + 512);    // 32 x 128B LSTM group lines
  u32* grpG = (u32*)(w + 4608);   // 16 x 128B GRU group lines

  hipMemsetAsync(d_ws, 0, BAR, stream);   // zero all barrier counters

#define LAUNCH(CG, CL, XSLOTS)                                                     \
  do {                                                                             \
    u16* xpp = (u16*)(w + BAR);                                                    \
    u16* hpp = (u16*)(w + BAR + (size_t)(XSLOTS) * XS);                            \
    gru_chain<CG><<<128, 256, 0, stream>>>(z, gWih, gWhh, gbih, gbhh,              \
                                           (u16*)d_out, xpp, grpG);                \
    lstm_fc_chain<CL><<<256, 1024, 0, stream>>>(lWih, lWhh, lbih, lbhh, fcW, fcb,  \
                                                hpp, (u16*)d_out, (float*)d_out,   \
                                                grpL);                             \
  } while (0)

  if      (ws_size >= BAR + 64 * XS + 128 * HS) LAUNCH(64, 128, 64);  // 83.9 MB
  else if (ws_size >= BAR + 32 * XS +  64 * HS) LAUNCH(32,  64, 32);  // 41.9 MB
  else if (ws_size >= BAR + 16 * XS +  32 * HS) LAUNCH(16,  32, 16);  // 21.0 MB
  else if (ws_size >= BAR +  8 * XS +  16 * HS) LAUNCH( 8,  16,  8);  // 10.5 MB
  else if (ws_size >= BAR +  2 * XS +   8 * HS) LAUNCH( 0,   8,  2);  //  4.7 MB (guaranteed: ws >= 5.77 MB proven in round 1)
  else return;

#undef LAUNCH
}

// Round 10
// 5369.771 us; speedup vs baseline: 1.6071x; 1.6071x over previous
//
#include <hip/hip_runtime.h>
#include <stdint.h>
#include <math.h>

// Decoder: autoregressive GRU (B=128,H=512,T=256) -> LSTM (L=1024) -> FC (V=1024)
// fp32 I/O. Internal math fp32; GEMMs via MFMA 16x16x32 bf16 with split-bf16
// (hi/lo) weights AND activations, 3-pass MFMA.
//
// Round 14: CROSS-BLOCK SPLIT-K PAIRS. Round 9 killed the occupancy theory
// (2x waves, 0 delta): per-CU read throughput is a ~30-33 GB/s issue-path
// wall, invariant to waves/layout/cache-level. Only lever: fewer bytes per CU.
// Pair (s, s^1): block s reads only k-half (s&1) of h (256KB vs 512KB) and
// seq (128KB vs 256KB) but computes gate partials for BOTH blocks' 4-col
// groups (32 weight rows in LDS at half-K). In-step exchange: sc-store 8KB
// fp32 partial to partner inbox -> drain -> flag -> poll -> sc-load -> sum ->
// gates. FC stays full-K, post-arrive (off the cycle). Fallback to round-9
// kernel if ws_size < pair tier (inbox needs +2.1MB).

typedef unsigned short u16;
typedef unsigned int u32;
typedef __attribute__((ext_vector_type(8))) short short8;   // 8 bf16 = 4 VGPR
typedef __attribute__((ext_vector_type(4))) float float4_;  // MFMA acc

#define MFMA(a, b, c) __builtin_amdgcn_mfma_f32_16x16x32_bf16((a), (b), (c), 0, 0, 0)

// System-coherent (LLC) 16B load, bypasses L1+L2; usable only after an owning wait.
#define SC_LOAD(dst, ptr) \
  asm volatile("global_load_dwordx4 %0, %1, off sc0 sc1" : "=v"(dst) : "v"(ptr) : "memory")
#define SC_LOADF(dst, ptr) \
  asm volatile("global_load_dwordx4 %0, %1, off sc0 sc1" : "=v"(dst) : "v"(ptr) : "memory")
// s_waitcnt that also "owns" loaded regs so consumers can't be hoisted above it.
#define WAIT8(n, a0,a1,a2,a3,a4,a5,a6,a7) \
  asm volatile("s_waitcnt vmcnt(" #n ")" \
    : "+v"(a0),"+v"(a1),"+v"(a2),"+v"(a3),"+v"(a4),"+v"(a5),"+v"(a6),"+v"(a7) :: "memory")
#define WAIT1F(a0) \
  asm volatile("s_waitcnt vmcnt(0)" : "+v"(a0) :: "memory")
// Coherent stores (write-through to LLC, complete when vmcnt retires).
#define SC_STORE16(ptr, val) \
  asm volatile("global_store_short %0, %1, off sc0 sc1" :: "v"(ptr), "v"((u32)(val)) : "memory")
#define SC_STORE128(ptr, val) \
  asm volatile("global_store_dwordx4 %0, %1, off sc0 sc1" :: "v"(ptr), "v"(val) : "memory")

__device__ __forceinline__ float bf2f(u16 u) {
  union { u32 i; float f; } v; v.i = ((u32)u) << 16; return v.f;
}
__device__ __forceinline__ u16 f2bf(float f) {
  union { float f; u32 i; } v; v.f = f;
  u32 x = v.i;
  return (u16)((x + 0x7fffu + ((x >> 16) & 1u)) >> 16);  // RNE, finite inputs only
}
__device__ __forceinline__ void split2(float w, u16& h, u16& l) {
  h = f2bf(w); l = f2bf(w - bf2f(h));
}
__device__ __forceinline__ float sigm(float x) { return 1.0f / (1.0f + expf(-x)); }

__device__ __forceinline__ void frag_from_f32(const float* p, short8& hi, short8& lo) {
  short8 h, l;
#pragma unroll
  for (int j = 0; j < 8; ++j) {
    u16 a, b; split2(p[j], a, b);
    h[j] = (short)a; l[j] = (short)b;
  }
  hi = h; lo = l;
}

// System-scope acquire: s_waitcnt + buffer_inv (invalidate-only, preserves dirty).
__device__ __forceinline__ void cache_acquire() {
  __builtin_amdgcn_fence(__ATOMIC_ACQUIRE, "");
}

// --- Flat group barrier (no root) ------------------------------------------
__device__ __forceinline__ void bar_arrive(u32* grp) {
  asm volatile("s_waitcnt vmcnt(0)" ::: "memory");
  __syncthreads();
  if (threadIdx.x == 0) atomicAdd(grp, 1u);
}
template<int NG>
__device__ __forceinline__ void bar_wait_poll(u32* grpb, u32 target) {
  if (threadIdx.x < 64) {
    u32* p = grpb + (size_t)(threadIdx.x & (NG - 1)) * 32;
    while (true) {
      u32 v = __hip_atomic_load(p, __ATOMIC_RELAXED, __HIP_MEMORY_SCOPE_AGENT);
      if (__all((int)(v >= target))) break;
      __builtin_amdgcn_s_sleep(1);
    }
  }
  __syncthreads();
}

// Tile-layout offset helpers (u16 units).
__device__ __forceinline__ size_t xoff(int r, int k) {
  return ((size_t)((r >> 4) * 16 + (k >> 5))) * 512 + (r & 15) * 32 + (k & 31);
}
__device__ __forceinline__ size_t hoff(int r, int k) {
  return ((size_t)((r >> 4) * 32 + (k >> 5))) * 512 + (r & 15) * 32 + (k & 31);
}

// ---------------------------------------------------------------------------
// Kernel 1: persistent GRU chain. 128 blocks x 256 threads. UNCHANGED (control).
// ---------------------------------------------------------------------------
template<int C>
__global__ __launch_bounds__(256)
void gru_chain(const float* __restrict__ z,
               const float* __restrict__ Wih, const float* __restrict__ Whh,
               const float* __restrict__ bih, const float* __restrict__ bhh,
               u16* outu, u16* __restrict__ xpp, u32* grpb) {
  __shared__ __align__(16) u16 wh_lds[48 * 520];
  __shared__ __align__(16) u16 wl_lds[48 * 520];
  __shared__ float blds[32];

  const int tid = threadIdx.x;
  const int wg = blockIdx.x;
  const int grp = wg & 63;
  const int mhalf = wg >> 6;
  const int jb = grp * 8;
  u32* const mygrp = grpb + (size_t)(wg >> 3) * 32;

  for (int idx = tid; idx < 48 * 512; idx += 256) {
    int row = idx >> 9, k = idx & 511;
    int t3 = row >> 4, n = row & 15;
    int grow = t3 * 512 + jb + (n & 7);
    float w = ((n < 8) ? Wih : Whh)[(size_t)grow * 512 + k];
    u16 h, l; split2(w, h, l);
    wh_lds[row * 520 + k] = h;
    wl_lds[row * 520 + k] = l;
  }
  if (tid < 8) {
    blds[tid]      = bih[jb + tid] + bhh[jb + tid];
    blds[8 + tid]  = bih[512 + jb + tid] + bhh[512 + jb + tid];
    blds[16 + tid] = bih[1024 + jb + tid];
    blds[24 + tid] = bhh[1024 + jb + tid];
  }
  __syncthreads();

  const int lane = tid & 63, wv = tid >> 6;
  const int n16 = lane & 15, q = lane >> 4;
  const int j8 = n16 & 7;
  const int mrow = mhalf * 64 + wv * 16 + n16;
  const int orow0 = mhalf * 64 + wv * 16 + q * 4;
  const bool act = (n16 < 8);
  const int col = jb + j8;
  const int qo = q * 8;
  const int xg = mhalf * 4 + wv;

  float x_own[4];

  {
    float4_ acc0 = {0.f, 0.f, 0.f, 0.f}, acc1 = acc0, acc2 = acc0;
    for (int ki = 0; ki < 16; ++ki) {
      const int ko = ki * 32 + qo;
      short8 ah, al;
      frag_from_f32(z + (size_t)mrow * 512 + ko, ah, al);
      short8 b0h = *(const short8*)(wh_lds + (0 * 16 + n16) * 520 + ko);
      short8 b1h = *(const short8*)(wh_lds + (1 * 16 + n16) * 520 + ko);
      short8 b2h = *(const short8*)(wh_lds + (2 * 16 + n16) * 520 + ko);
      short8 b0l = *(const short8*)(wl_lds + (0 * 16 + n16) * 520 + ko);
      short8 b1l = *(const short8*)(wl_lds + (1 * 16 + n16) * 520 + ko);
      short8 b2l = *(const short8*)(wl_lds + (2 * 16 + n16) * 520 + ko);
      acc0 = MFMA(ah, b0h, acc0); acc0 = MFMA(al, b0h, acc0); acc0 = MFMA(ah, b0l, acc0);
      acc1 = MFMA(ah, b1h, acc1); acc1 = MFMA(al, b1h, acc1); acc1 = MFMA(ah, b1l, acc1);
      acc2 = MFMA(ah, b2h, acc2); acc2 = MFMA(al, b2h, acc2); acc2 = MFMA(ah, b2l, acc2);
    }
    for (int reg = 0; reg < 4; ++reg) {
      float pr = __shfl_xor(acc0[reg], 8);
      float pz = __shfl_xor(acc1[reg], 8);
      float pn = __shfl_xor(acc2[reg], 8);
      float r  = sigm(pr + blds[j8]);
      float zg = sigm(pz + blds[8 + j8]);
      float nn = tanhf(blds[16 + j8] + r * (pn + blds[24 + j8]));
      float hv = act ? z[(size_t)(orow0 + reg) * 512 + col] : 0.f;
      float xn = (1.f - zg) * nn + zg * hv;
      x_own[reg] = xn;
      if (act) {
        size_t po = xoff(orow0 + reg, col);
        u16 h, l; split2(xn, h, l);
        SC_STORE16(xpp + (size_t)1 * 131072 + po, h);
        SC_STORE16(xpp + (size_t)1 * 131072 + 65536 + po, l);
      }
    }
  }
  bar_arrive(mygrp);
  if (act) {
    for (int reg = 0; reg < 4; ++reg) {
      int row = orow0 + reg;
      float rl = fmaxf(x_own[reg], 0.f);
      u16 rh, rlo; split2(rl, rh, rlo);
      size_t B = ((size_t)row * 256 + 1) * 2048;
      u32 rot = (u32)(row & 15) * 128;
      outu[B + ((rot + col) & 2047)] = rh;
      outu[B + ((rot + 512 + col) & 2047)] = rlo;
    }
  }
  bar_wait_poll<16>(grpb, 8u);

  for (int t = 2; t < 256; ++t) {
    if constexpr (C > 0) {
      if ((t & (C - 1)) == 0) cache_acquire();
    }
    const size_t sr = (C > 0) ? (size_t)((t - 1) & (C - 1)) : (size_t)((t - 1) & 1);
    const size_t sw = (C > 0) ? (size_t)(t & (C - 1))       : (size_t)(t & 1);
    const u16* xh = xpp + sr * 131072 + (size_t)xg * 16 * 512 + n16 * 32 + qo;
    const u16* xl = xh + 65536;
    short8 bufh[16], bufl[16];
    if constexpr (C > 0) {
#pragma unroll
      for (int ki = 0; ki < 16; ++ki) {
        bufh[ki] = *(const short8*)(xh + ki * 512);
        bufl[ki] = *(const short8*)(xl + ki * 512);
      }
    } else {
#pragma unroll
      for (int ki = 0; ki < 16; ++ki) {
        SC_LOAD(bufh[ki], xh + ki * 512);
        SC_LOAD(bufl[ki], xl + ki * 512);
      }
      WAIT8(0, bufh[0], bufh[1], bufh[2], bufh[3], bufh[4], bufh[5], bufh[6], bufh[7]);
      WAIT8(0, bufh[8], bufh[9], bufh[10], bufh[11], bufh[12], bufh[13], bufh[14], bufh[15]);
      WAIT8(0, bufl[0], bufl[1], bufl[2], bufl[3], bufl[4], bufl[5], bufl[6], bufl[7]);
      WAIT8(0, bufl[8], bufl[9], bufl[10], bufl[11], bufl[12], bufl[13], bufl[14], bufl[15]);
    }

    float4_ acc0 = {0.f, 0.f, 0.f, 0.f}, acc1 = acc0, acc2 = acc0;
#pragma unroll
    for (int ki = 0; ki < 16; ++ki) {
      const int ko = ki * 32 + qo;
      short8 b0h = *(const short8*)(wh_lds + (0 * 16 + n16) * 520 + ko);
      short8 b1h = *(const short8*)(wh_lds + (1 * 16 + n16) * 520 + ko);
      short8 b2h = *(const short8*)(wh_lds + (2 * 16 + n16) * 520 + ko);
      short8 b0l = *(const short8*)(wl_lds + (0 * 16 + n16) * 520 + ko);
      short8 b1l = *(const short8*)(wl_lds + (1 * 16 + n16) * 520 + ko);
      short8 b2l = *(const short8*)(wl_lds + (2 * 16 + n16) * 520 + ko);
      acc0 = MFMA(bufh[ki], b0h, acc0); acc0 = MFMA(bufl[ki], b0h, acc0); acc0 = MFMA(bufh[ki], b0l, acc0);
      acc1 = MFMA(bufh[ki], b1h, acc1); acc1 = MFMA(bufl[ki], b1h, acc1); acc1 = MFMA(bufh[ki], b1l, acc1);
      acc2 = MFMA(bufh[ki], b2h, acc2); acc2 = MFMA(bufl[ki], b2h, acc2); acc2 = MFMA(bufh[ki], b2l, acc2);
    }
    for (int reg = 0; reg < 4; ++reg) {
      float ar = acc0[reg], az = acc1[reg], an = acc2[reg];
      float pr = __shfl_xor(ar, 8), pz = __shfl_xor(az, 8), pn = __shfl_xor(an, 8);
      float r  = sigm(ar + pr + blds[j8]);
      float zg = sigm(az + pz + blds[8 + j8]);
      float nn = tanhf(an + blds[16 + j8] + r * (pn + blds[24 + j8]));
      float xn = (1.f - zg) * nn + zg * x_own[reg];
      x_own[reg] = xn;
      if (act) {
        size_t po = xoff(orow0 + reg, col);
        u16 h, l; split2(xn, h, l);
        SC_STORE16(xpp + sw * 131072 + po, h);
        SC_STORE16(xpp + sw * 131072 + 65536 + po, l);
      }
    }
    if (t < 255) bar_arrive(mygrp);
    if (act) {
      for (int reg = 0; reg < 4; ++reg) {
        int row = orow0 + reg;
        float rl = fmaxf(x_own[reg], 0.f);
        u16 rh, rlo; split2(rl, rh, rlo);
        size_t B = ((size_t)row * 256 + (size_t)t) * 2048;
        u32 rot = (u32)(row & 15) * 128;
        outu[B + ((rot + col) & 2047)] = rh;
        outu[B + ((rot + 512 + col) & 2047)] = rlo;
      }
    }
    if (t < 255) bar_wait_poll<16>(grpb, (u32)t * 8u);
  }
}

// ---------------------------------------------------------------------------
// Kernel 2 (NEW): pair-split-K LSTM. 256 blocks x 1024 threads, 1 block/CU.
// Block s: k-half (s&1) of h/seq, gate partials for BOTH pair members' 4-col
// groups (32 weight rows, half-K LDS). Exchange partner partial via sc stores
// + flag + sc loads. FC full-K, post-arrive. Ring mode only (C >= 8).
// ---------------------------------------------------------------------------
template<int C>
__global__ __launch_bounds__(1024)
void lstm_pair(const float* __restrict__ Wih, const float* __restrict__ Whh,
               const float* __restrict__ bih, const float* __restrict__ bhh,
               const float* __restrict__ fcW, const float* __restrict__ fcb,
               u16* __restrict__ hpp, u16* outu, float* outf, u32* grpb,
               float* __restrict__ xbuf, u32* __restrict__ xflag) {
  static_assert(C >= 8, "pair LSTM requires ring mode");
  __shared__ __align__(16) u16 whh_hi[32 * 512];   // [cg*16+r16][k-half], swizzled
  __shared__ __align__(16) u16 whh_lo[32 * 512];
  __shared__ __align__(16) u16 wih_hi[32 * 256];
  __shared__ __align__(16) u16 wih_lo[32 * 256];
  __shared__ float glds[2][128][16];               // [cg][row][gate*4+cc], kq-accumulated
  __shared__ float pglds[2][16][8][16];
  __shared__ float bclds[16];
  __shared__ float fclds[16];

  const int tid = threadIdx.x;
  const int s = blockIdx.x;
  const int khalf = s & 1;
  const int ps = s ^ 1;
  const int colbase = s * 4;
  const int vt = s & 63, bq = s >> 6;
  const int vbase = vt * 16;
  u32* const mygrp = grpb + (size_t)(s >> 3) * 32;

  // weights: 32 rows = [cg 2][gate 4][cc 4], k restricted to this block's half
  for (int idx = tid; idx < 32 * 512; idx += 1024) {
    int wrow = idx >> 9, k = idx & 511;
    int cg = wrow >> 4, r16 = wrow & 15;
    int gate = r16 >> 2, cc = r16 & 3;
    int gcol = (cg ? ps : s) * 4 + cc;
    float w = Whh[(size_t)(gate * 1024 + gcol) * 1024 + khalf * 512 + k];
    u16 h, l; split2(w, h, l);
    int ks2 = k ^ ((r16 & 7) << 3);
    whh_hi[wrow * 512 + ks2] = h;
    whh_lo[wrow * 512 + ks2] = l;
  }
  for (int idx = tid; idx < 32 * 256; idx += 1024) {
    int wrow = idx >> 8, k = idx & 255;
    int cg = wrow >> 4, r16 = wrow & 15;
    int gate = r16 >> 2, cc = r16 & 3;
    int gcol = (cg ? ps : s) * 4 + cc;
    float w = Wih[(size_t)(gate * 1024 + gcol) * 512 + khalf * 256 + k];
    u16 h, l; split2(w, h, l);
    int ks2 = k ^ ((r16 & 7) << 3);
    wih_hi[wrow * 256 + ks2] = h;
    wih_lo[wrow * 256 + ks2] = l;
  }
  if (tid < 16) {
    int gate = tid >> 2, cc = tid & 3;
    int wcol = gate * 1024 + colbase + cc;
    bclds[tid] = bih[wcol] + bhh[wcol];
    fclds[tid] = fcb[vbase + tid];
  }
  __syncthreads();

  const int lane = tid & 63, wv16 = tid >> 6;   // 16 waves
  const int wv = wv16 & 7;                      // row-group (16 h-rows)
  const int kq = wv16 >> 3;                     // k-quarter within block half
  const int n16 = lane & 15, q = lane >> 4;
  const int qo = q * 8;
  const int nsw = (n16 & 7) << 3;
  const int arow = wv * 16 + n16;
  const int myrow = tid >> 2, mycol = tid & 3;  // valid for tid < 512
  const int fmt = wv16 & 1, fkq = wv16 >> 1;    // FC: 2 row-halves x 8 k-chunks
  const int fkbase = fkq * 128;
  const int fg = bq * 2 + fmt;

  short8 brh[4], brl[4];
  for (int i = 0; i < 4; ++i)
    frag_from_f32(fcW + (size_t)(vbase + n16) * 1024 + fkbase + i * 32 + qo,
                  brh[i], brl[i]);

  float* const inbox  = xbuf + (size_t)s * 2048;   // my inbox (partner writes)
  float* const outbox = xbuf + (size_t)ps * 2048;  // partner's inbox (I write)
  u32* const myflag = xflag + (size_t)s * 32;
  u32* const pflag  = xflag + (size_t)ps * 32;

  float c = 0.f;

  // t = 0: preacts are just biases; write h_0 into slot 0, arrive gen 1.
  if (tid < 512) {
    float pi = bclds[mycol], pg = bclds[8 + mycol], po = bclds[12 + mycol];
    c = sigm(pi) * tanhf(pg);
    float h = sigm(po) * tanhf(c);
    size_t off = hoff(myrow, colbase + mycol);
    u16 hh, hl; split2(h, hh, hl);
    SC_STORE16(hpp + off, hh);
    SC_STORE16(hpp + 131072 + off, hl);
  }
  bar_arrive(mygrp);   // gen 1

  for (int t = 1; t < 256; ++t) {
    const size_t sr = (size_t)((t - 1) & (C - 1));
    const size_t sw = (size_t)(t & (C - 1));

    // ---- pre-wait: seq, this k-half, this wave's quarter, BOTH col-groups ----
    float4_ accO = {0.f, 0.f, 0.f, 0.f}, accP = accO;
    {
      const u16* sqB = outu + ((size_t)arow * 256 + t) * 2048;
      const int rot = n16 * 128;
#pragma unroll
      for (int i = 0; i < 4; ++i) {
        const int lk = kq * 128 + i * 32 + qo;   // [0,256) local to k-half
        const int gko = khalf * 256 + lk;        // [0,512) global seq k
        const int kw = lk ^ nsw;
        short8 sh = *(const short8*)(sqB + ((rot + gko) & 2047));
        short8 sl = *(const short8*)(sqB + ((rot + 512 + gko) & 2047));
        short8 bh0 = *(const short8*)(wih_hi + n16 * 256 + kw);
        short8 bl0 = *(const short8*)(wih_lo + n16 * 256 + kw);
        short8 bh1 = *(const short8*)(wih_hi + (16 + n16) * 256 + kw);
        short8 bl1 = *(const short8*)(wih_lo + (16 + n16) * 256 + kw);
        accO = MFMA(sh, bh0, accO); accO = MFMA(sl, bh0, accO); accO = MFMA(sh, bl0, accO);
        accP = MFMA(sh, bh1, accP); accP = MFMA(sl, bh1, accP); accP = MFMA(sh, bl1, accP);
      }
    }

    if ((t & (C - 1)) == 0) cache_acquire();   // kill stale ring lines
    bar_wait_poll<32>(grpb, (u32)t * 8u);      // h_{t-1} now visible

    // ---- h: rows wv*16, k [khalf*512 + kq*256, +256) -- 8 contiguous tiles ----
    {
      const u16* ph = hpp + sr * 262144 +
                      ((size_t)wv * 32 + khalf * 16 + kq * 8) * 512 + n16 * 32 + qo;
      const u16* pl = ph + 131072;
      short8 hb[8], lb[8];
#pragma unroll
      for (int j = 0; j < 8; ++j) {
        hb[j] = *(const short8*)(ph + j * 512);
        lb[j] = *(const short8*)(pl + j * 512);
      }
#pragma unroll
      for (int j = 0; j < 8; ++j) {
        const int lk = kq * 256 + j * 32 + qo;   // [0,512) local to k-half
        const int kw = lk ^ nsw;
        short8 bh0 = *(const short8*)(whh_hi + n16 * 512 + kw);
        short8 bl0 = *(const short8*)(whh_lo + n16 * 512 + kw);
        short8 bh1 = *(const short8*)(whh_hi + (16 + n16) * 512 + kw);
        short8 bl1 = *(const short8*)(whh_lo + (16 + n16) * 512 + kw);
        accO = MFMA(hb[j], bh0, accO); accO = MFMA(lb[j], bh0, accO); accO = MFMA(hb[j], bl0, accO);
        accP = MFMA(hb[j], bh1, accP); accP = MFMA(lb[j], bh1, accP); accP = MFMA(hb[j], bl1, accP);
      }
    }
    // kq-accumulate into glds: kq0 writes, kq1 adds
    if (kq == 0) {
      for (int reg = 0; reg < 4; ++reg) {
        glds[0][wv * 16 + q * 4 + reg][n16] = accO[reg];
        glds[1][wv * 16 + q * 4 + reg][n16] = accP[reg];
      }
    }
    __syncthreads();
    if (kq == 1) {
      for (int reg = 0; reg < 4; ++reg) {
        glds[0][wv * 16 + q * 4 + reg][n16] += accO[reg];
        glds[1][wv * 16 + q * 4 + reg][n16] += accP[reg];
      }
    }
    __syncthreads();

    // ---- send partner partial: inbox layout [row*16 + mycol*4 + gate] ----
    if (tid < 512) {
      int srow = tid >> 2, sc4 = tid & 3;
      float4_ v;
#pragma unroll
      for (int g = 0; g < 4; ++g)
        v[g] = glds[1][srow][g * 4 + sc4];
      SC_STORE128(outbox + (size_t)srow * 16 + sc4 * 4, v);
    }
    asm volatile("s_waitcnt vmcnt(0)" ::: "memory");
    __syncthreads();
    if (tid == 0) {
      atomicAdd(pflag, 1u);
      while (__hip_atomic_load(myflag, __ATOMIC_RELAXED, __HIP_MEMORY_SCOPE_AGENT) < (u32)t)
        __builtin_amdgcn_s_sleep(1);
    }
    __syncthreads();

    // ---- recv + gates + h-store ----
    if (tid < 512) {
      float4_ rv;
      SC_LOADF(rv, inbox + (size_t)tid * 4);
      WAIT1F(rv);
      float pi = glds[0][myrow][mycol]      + rv[0] + bclds[mycol];
      float pf = glds[0][myrow][4 + mycol]  + rv[1] + bclds[4 + mycol];
      float pg = glds[0][myrow][8 + mycol]  + rv[2] + bclds[8 + mycol];
      float po = glds[0][myrow][12 + mycol] + rv[3] + bclds[12 + mycol];
      c = sigm(pf) * c + sigm(pi) * tanhf(pg);
      float h = sigm(po) * tanhf(c);
      size_t off = hoff(myrow, colbase + mycol);
      u16 hh, hl; split2(h, hh, hl);
      SC_STORE16(hpp + sw * 262144 + off, hh);
      SC_STORE16(hpp + sw * 262144 + 131072 + off, hl);
    }
    bar_arrive(mygrp);   // gen t+1 (early; FC below not consumed by others)

    // ---- fused FC: logits_{t-1} from h_{t-1} (slot sr), full K, tiled ----
    {
      const u16* fh = hpp + sr * 262144 + ((size_t)fg * 32 + fkq * 4) * 512 + n16 * 32 + qo;
      const u16* fl = fh + 131072;
      short8 fhb[4], flb[4];
#pragma unroll
      for (int i = 0; i < 4; ++i) {
        fhb[i] = *(const short8*)(fh + i * 512);
        flb[i] = *(const short8*)(fl + i * 512);
      }
      float4_ lacc = {0.f, 0.f, 0.f, 0.f};
#pragma unroll
      for (int i = 0; i < 4; ++i) {
        lacc = MFMA(fhb[i], brh[i], lacc);
        lacc = MFMA(flb[i], brh[i], lacc);
        lacc = MFMA(fhb[i], brl[i], lacc);
      }
      for (int reg = 0; reg < 4; ++reg)
        pglds[fmt][q * 4 + reg][fkq][n16] = lacc[reg];
      __syncthreads();
      if (tid < 512) {
        int trow = tid >> 4, tcol = tid & 15;
        const float* pg8 = &pglds[trow >> 4][trow & 15][0][tcol];
        float lsum = fclds[tcol];
#pragma unroll
        for (int f = 0; f < 8; ++f) lsum += pg8[f * 16];
        outf[((size_t)(bq * 32 + trow) * 256 + (t - 1)) * 1024 + vbase + tcol] = lsum;
      }
    }
  }

  // epilogue: logits_255 from h_255
  {
    bar_wait_poll<32>(grpb, 256u * 8u);
    cache_acquire();
    const size_t sl = (size_t)(255 & (C - 1));
    const u16* fh = hpp + sl * 262144 + ((size_t)fg * 32 + fkq * 4) * 512 + n16 * 32 + qo;
    const u16* fl = fh + 131072;
    short8 fhb[4], flb[4];
#pragma unroll
    for (int i = 0; i < 4; ++i) {
      fhb[i] = *(const short8*)(fh + i * 512);
      flb[i] = *(const short8*)(fl + i * 512);
    }
    float4_ lacc = {0.f, 0.f, 0.f, 0.f};
#pragma unroll
    for (int i = 0; i < 4; ++i) {
      lacc = MFMA(fhb[i], brh[i], lacc);
      lacc = MFMA(flb[i], brh[i], lacc);
      lacc = MFMA(fhb[i], brl[i], lacc);
    }
    for (int reg = 0; reg < 4; ++reg)
      pglds[fmt][q * 4 + reg][fkq][n16] = lacc[reg];
    __syncthreads();
    if (tid < 512) {
      int trow = tid >> 4, tcol = tid & 15;
      const float* pg8 = &pglds[trow >> 4][trow & 15][0][tcol];
      float lsum = fclds[tcol];
#pragma unroll
      for (int f = 0; f < 8; ++f) lsum += pg8[f * 16];
      outf[((size_t)(bq * 32 + trow) * 256 + 255) * 1024 + vbase + tcol] = lsum;
    }
  }
}

// ---------------------------------------------------------------------------
// Kernel 2 FALLBACK (round-9 split-K-in-block, 1024 threads): used when ws is
// too small for the pair inbox region.
// ---------------------------------------------------------------------------
template<int C>
__global__ __launch_bounds__(1024)
void lstm_r9(const float* __restrict__ Wih, const float* __restrict__ Whh,
             const float* __restrict__ bih, const float* __restrict__ bhh,
             const float* __restrict__ fcW, const float* __restrict__ fcb,
             u16* __restrict__ hpp, u16* outu, float* outf, u32* grpb) {
  static_assert(C >= 8, "LSTM requires ring mode");
  __shared__ __align__(16) u16 whh_hi[16 * 1024];
  __shared__ __align__(16) u16 whh_lo[16 * 1024];
  __shared__ __align__(16) u16 wih_hi[16 * 512];
  __shared__ __align__(16) u16 wih_lo[16 * 512];
  __shared__ float glds[2][128][17];
  __shared__ float pglds[2][16][8][16];
  __shared__ float bclds[16];
  __shared__ float fclds[16];

  const int tid = threadIdx.x;
  const int s = blockIdx.x;
  const int colbase = s * 4;
  const int vt = s & 63, bq = s >> 6;
  const int vbase = vt * 16;
  u32* const mygrp = grpb + (size_t)(s >> 3) * 32;

  for (int idx = tid; idx < 16 * 1024; idx += 1024) {
    int row = idx >> 10, k = idx & 1023;
    int gate = row >> 2, cc = row & 3;
    float w = Whh[(size_t)(gate * 1024 + colbase + cc) * 1024 + k];
    u16 h, l; split2(w, h, l);
    int ks2 = k ^ ((row & 7) << 3);
    whh_hi[row * 1024 + ks2] = h;
    whh_lo[row * 1024 + ks2] = l;
  }
  for (int idx = tid; idx < 16 * 512; idx += 1024) {
    int row = idx >> 9, k = idx & 511;
    int gate = row >> 2, cc = row & 3;
    float w = Wih[(size_t)(gate * 1024 + colbase + cc) * 512 + k];
    u16 h, l; split2(w, h, l);
    int ks2 = k ^ ((row & 7) << 3);
    wih_hi[row * 512 + ks2] = h;
    wih_lo[row * 512 + ks2] = l;
  }
  if (tid < 16) {
    int gate = tid >> 2, cc = tid & 3;
    int wcol = gate * 1024 + colbase + cc;
    bclds[tid] = bih[wcol] + bhh[wcol];
    fclds[tid] = fcb[vbase + tid];
  }
  __syncthreads();

  const int lane = tid & 63, wv16 = tid >> 6;
  const int wv = wv16 & 7;
  const int ks = wv16 >> 3;
  const int n16 = lane & 15, q = lane >> 4;
  const int qo = q * 8;
  const int nsw = (n16 & 7) << 3;
  const int arow = wv * 16 + n16;
  const int myrow = tid >> 2, mycol = tid & 3;
  const int fmt = wv16 & 1, fkq = wv16 >> 1;
  const int fkbase = fkq * 128;
  const int fg = bq * 2 + fmt;

  short8 brh[4], brl[4];
  for (int i = 0; i < 4; ++i)
    frag_from_f32(fcW + (size_t)(vbase + n16) * 1024 + fkbase + i * 32 + qo,
                  brh[i], brl[i]);

  float c = 0.f;

  if (tid < 512) {
    float pi = bclds[mycol], pg = bclds[8 + mycol], po = bclds[12 + mycol];
    c = sigm(pi) * tanhf(pg);
    float h = sigm(po) * tanhf(c);
    size_t off = hoff(myrow, colbase + mycol);
    u16 hh, hl; split2(h, hh, hl);
    SC_STORE16(hpp + off, hh);
    SC_STORE16(hpp + 131072 + off, hl);
  }
  bar_arrive(mygrp);

  for (int t = 1; t < 256; ++t) {
    const size_t sr = (size_t)((t - 1) & (C - 1));
    const size_t sw = (size_t)(t & (C - 1));

    float4_ acc = {0.f, 0.f, 0.f, 0.f};
    {
      const u16* sqB = outu + ((size_t)arow * 256 + t) * 2048;
      const int rot = n16 * 128;
#pragma unroll
      for (int kk = 0; kk < 8; ++kk) {
        const int ki = ks * 8 + kk;
        const int ko = ki * 32 + qo;
        const int kw = ko ^ nsw;
        short8 sh = *(const short8*)(sqB + ((rot + ko) & 2047));
        short8 sl = *(const short8*)(sqB + ((rot + 512 + ko) & 2047));
        short8 bh = *(const short8*)(wih_hi + n16 * 512 + kw);
        short8 bl = *(const short8*)(wih_lo + n16 * 512 + kw);
        acc = MFMA(sh, bh, acc); acc = MFMA(sl, bh, acc); acc = MFMA(sh, bl, acc);
      }
    }

    if ((t & (C - 1)) == 0) cache_acquire();
    bar_wait_poll<32>(grpb, (u32)t * 8u);

    const u16* ph = hpp + sr * 262144 + (size_t)wv * 32 * 512 + n16 * 32 + qo;
    const u16* pl = ph + 131072;
#pragma unroll
    for (int cc2 = 0; cc2 < 2; ++cc2) {
      const int ch = ks * 2 + cc2;
      short8 hb[8], lb[8];
#pragma unroll
      for (int j = 0; j < 8; ++j) {
        hb[j] = *(const short8*)(ph + (ch * 8 + j) * 512);
        lb[j] = *(const short8*)(pl + (ch * 8 + j) * 512);
      }
#pragma unroll
      for (int j = 0; j < 8; ++j) {
        const int ko = (ch * 8 + j) * 32 + qo;
        const int kw = ko ^ nsw;
        short8 bh = *(const short8*)(whh_hi + n16 * 1024 + kw);
        short8 bl = *(const short8*)(whh_lo + n16 * 1024 + kw);
        acc = MFMA(hb[j], bh, acc);
        acc = MFMA(lb[j], bh, acc);
        acc = MFMA(hb[j], bl, acc);
      }
    }
    for (int reg = 0; reg < 4; ++reg)
      glds[ks][wv * 16 + q * 4 + reg][n16] = acc[reg];
    __syncthreads();
    if (tid < 512) {
      float pi = glds[0][myrow][mycol]      + glds[1][myrow][mycol]      + bclds[mycol];
      float pf = glds[0][myrow][4 + mycol]  + glds[1][myrow][4 + mycol]  + bclds[4 + mycol];
      float pg = glds[0][myrow][8 + mycol]  + glds[1][myrow][8 + mycol]  + bclds[8 + mycol];
      float po = glds[0][myrow][12 + mycol] + glds[1][myrow][12 + mycol] + bclds[12 + mycol];
      c = sigm(pf) * c + sigm(pi) * tanhf(pg);
      float h = sigm(po) * tanhf(c);
      size_t off = hoff(myrow, colbase + mycol);
      u16 hh, hl; split2(h, hh, hl);
      SC_STORE16(hpp + sw * 262144 + off, hh);
      SC_STORE16(hpp + sw * 262144 + 131072 + off, hl);
    }
    bar_arrive(mygrp);

    {
      const u16* fh = hpp + sr * 262144 + ((size_t)fg * 32 + fkq * 4) * 512 + n16 * 32 + qo;
      const u16* fl = fh + 131072;
      short8 fhb[4], flb[4];
#pragma unroll
      for (int i = 0; i < 4; ++i) {
        fhb[i] = *(const short8*)(fh + i * 512);
        flb[i] = *(const short8*)(fl + i * 512);
      }
      float4_ lacc = {0.f, 0.f, 0.f, 0.f};
#pragma unroll
      for (int i = 0; i < 4; ++i) {
        lacc = MFMA(fhb[i], brh[i], lacc);
        lacc = MFMA(flb[i], brh[i], lacc);
        lacc = MFMA(fhb[i], brl[i], lacc);
      }
      for (int reg = 0; reg < 4; ++reg)
        pglds[fmt][q * 4 + reg][fkq][n16] = lacc[reg];
      __syncthreads();
      if (tid < 512) {
        int trow = tid >> 4, tcol = tid & 15;
        const float* pg8 = &pglds[trow >> 4][trow & 15][0][tcol];
        float lsum = fclds[tcol];
#pragma unroll
        for (int f = 0; f < 8; ++f) lsum += pg8[f * 16];
        outf[((size_t)(bq * 32 + trow) * 256 + (t - 1)) * 1024 + vbase + tcol] = lsum;
      }
    }
  }

  {
    bar_wait_poll<32>(grpb, 256u * 8u);
    cache_acquire();
    const size_t sl = (size_t)(255 & (C - 1));
    const u16* fh = hpp + sl * 262144 + ((size_t)fg * 32 + fkq * 4) * 512 + n16 * 32 + qo;
    const u16* fl = fh + 131072;
    short8 fhb[4], flb[4];
#pragma unroll
    for (int i = 0; i < 4; ++i) {
      fhb[i] = *(const short8*)(fh + i * 512);
      flb[i] = *(const short8*)(fl + i * 512);
    }
    float4_ lacc = {0.f, 0.f, 0.f, 0.f};
#pragma unroll
    for (int i = 0; i < 4; ++i) {
      lacc = MFMA(fhb[i], brh[i], lacc);
      lacc = MFMA(flb[i], brh[i], lacc);
      lacc = MFMA(fhb[i], brl[i], lacc);
    }
    for (int reg = 0; reg < 4; ++reg)
      pglds[fmt][q * 4 + reg][fkq][n16] = lacc[reg];
    __syncthreads();
    if (tid < 512) {
      int trow = tid >> 4, tcol = tid & 15;
      const float* pg8 = &pglds[trow >> 4][trow & 15][0][tcol];
      float lsum = fclds[tcol];
#pragma unroll
      for (int f = 0; f < 8; ++f) lsum += pg8[f * 16];
      outf[((size_t)(bq * 32 + trow) * 256 + 255) * 1024 + vbase + tcol] = lsum;
    }
  }
}

// ---------------------------------------------------------------------------
extern "C" void kernel_launch(void* const* d_in, const int* in_sizes, int n_in,
                              void* d_out, int out_size, void* d_ws, size_t ws_size,
                              hipStream_t stream) {
  (void)in_sizes; (void)n_in; (void)out_size;
  const float* z    = (const float*)d_in[0];
  const float* gWih = (const float*)d_in[2];
  const float* gWhh = (const float*)d_in[3];
  const float* gbih = (const float*)d_in[4];
  const float* gbhh = (const float*)d_in[5];
  const float* lWih = (const float*)d_in[6];
  const float* lWhh = (const float*)d_in[7];
  const float* lbih = (const float*)d_in[8];
  const float* lbhh = (const float*)d_in[9];
  const float* fcW  = (const float*)d_in[10];
  const float* fcb  = (const float*)d_in[11];

  const size_t XS = 262144;       // x slot bytes (tiled)
  const size_t HS = 524288;       // h slot bytes (tiled)
  const size_t BAR = 8192;        // 32 LSTM + 16 GRU group lines
  const size_t XFLAG = 32768;     // 256 x 128B pair flags (at 8192)
  const size_t XBUF = 2097152;    // 256 x 8KB pair inboxes (at 65536)
  const size_t PBASE = 65536 + XBUF;   // rings start here in pair mode

  char* w = (char*)d_ws;
  u32* grpL  = (u32*)(w + 512);
  u32* grpG  = (u32*)(w + 4608);
  u32* xflag = (u32*)(w + BAR);
  float* xbuf = (float*)(w + 65536);
  (void)XFLAG;

#define LAUNCH_PAIR(CG, CL, XSLOTS)                                                \
  do {                                                                             \
    hipMemsetAsync(d_ws, 0, 40960, stream);                                        \
    u16* xpp = (u16*)(w + PBASE);                                                  \
    u16* hpp = (u16*)(w + PBASE + (size_t)(XSLOTS) * XS);                          \
    gru_chain<CG><<<128, 256, 0, stream>>>(z, gWih, gWhh, gbih, gbhh,              \
                                           (u16*)d_out, xpp, grpG);                \
    lstm_pair<CL><<<256, 1024, 0, stream>>>(lWih, lWhh, lbih, lbhh, fcW, fcb,      \
                                            hpp, (u16*)d_out, (float*)d_out,       \
                                            grpL, xbuf, xflag);                    \
  } while (0)

  if      (ws_size >= PBASE + 64 * XS + 128 * HS) LAUNCH_PAIR(64, 128, 64);
  else if (ws_size >= PBASE + 32 * XS +  64 * HS) LAUNCH_PAIR(32,  64, 32);
  else if (ws_size >= PBASE + 16 * XS +  32 * HS) LAUNCH_PAIR(16,  32, 16);
  else if (ws_size >= PBASE +  8 * XS +  16 * HS) LAUNCH_PAIR( 8,  16,  8);
  else if (ws_size >= PBASE +  2 * XS +   8 * HS) LAUNCH_PAIR( 0,   8,  2);  // 6.9 MB
  else if (ws_size >= BAR + 2 * XS + 8 * HS) {                               // 4.7 MB fallback
    hipMemsetAsync(d_ws, 0, BAR, stream);
    u16* xpp = (u16*)(w + BAR);
    u16* hpp = (u16*)(w + BAR + 2 * XS);
    gru_chain<0><<<128, 256, 0, stream>>>(z, gWih, gWhh, gbih, gbhh,
                                          (u16*)d_out, xpp, grpG);
    lstm_r9<8><<<256, 1024, 0, stream>>>(lWih, lWhh, lbih, lbhh, fcW, fcb,
                                         hpp, (u16*)d_out, (float*)d_out, grpL);
  } else return;

#undef LAUNCH_PAIR
}